// Round 14
// baseline (1168.400 us; speedup 1.0000x reference)
//
#include <hip/hip_runtime.h>
#include <hip/hip_bf16.h>
#include <math.h>

// GPT forward, bf16 MFMA GEMMs + f32 residual stream.
// Dims: L=4, B=2, S=1024, E=1024, H=16, HD=64, FF=6144, V=32000, tokens T=2048.

typedef unsigned short ushort_t;
typedef unsigned short us8 __attribute__((ext_vector_type(8)));
typedef unsigned short us4 __attribute__((ext_vector_type(4)));
typedef __bf16 bf16x8 __attribute__((ext_vector_type(8)));
typedef float f32x4 __attribute__((ext_vector_type(4)));

#define LN_EPS 1e-5f

__device__ inline ushort_t f2bf(float f) {
    union { float f; unsigned u; } v; v.f = f;
    unsigned r = v.u + 0x7FFFu + ((v.u >> 16) & 1u);   // RNE
    return (ushort_t)(r >> 16);
}

__device__ inline ushort_t bf16u(float f) {   // hw cvt
    __hip_bfloat16 h = __float2bfloat16(f);
    return *(ushort_t*)&h;
}

#define GLD_LDS16(gp, lp)                                                  \
    __builtin_amdgcn_global_load_lds(                                      \
        (const __attribute__((address_space(1))) unsigned int*)(gp),       \
        (__attribute__((address_space(3))) unsigned int*)(lp), 16, 0, 0)

enum { EPI_F32 = 0, EPI_BF16 = 1, EPI_ADDF32 = 2, EPI_GELU = 3, EPI_TBF16 = 4,
       EPI_ATOM = 5, EPI_QKV = 6 };

// ---------------------------------------------------------------------------
// gemm8ph: 8-phase 256x256 GEMM (r7 v1 schedule, measured best).
// NEW: EPI_F32 epilogue bounces acc through LDS (2 x 128KB chunks, cg-XOR
// 16-col swizzle) so global stores are 32 x float4/thread in 1KB wave runs
// instead of 128 scalar dwords in 64B runs.
// ---------------------------------------------------------------------------
template<int EPI>
__global__ __launch_bounds__(512)
void gemm8ph(const ushort_t* __restrict__ A, const ushort_t* __restrict__ B,
             void* __restrict__ Cv, int mt, int K, int lda, int ldb, int ldc)
{
    extern __shared__ ushort_t smem[];   // 2 x (16384 A + 16384 B) ushorts

    const int nwg  = gridDim.x;
    const int orig = blockIdx.x;
    int wgid = orig;
    if (nwg >= 8) {
        const int q = nwg >> 3, r = nwg & 7;
        const int xcd = orig & 7, i = orig >> 3;
        wgid = (xcd < r ? xcd * (q + 1) : r * (q + 1) + (xcd - r) * q) + i;
    }
    const int m0 = (wgid % mt) * 256;
    const int n0 = (wgid / mt) * 256;

    const int tid  = threadIdx.x;
    const int lane = tid & 63;
    const int wid  = tid >> 6;
    const int wm   = wid >> 2, wn = wid & 3;   // 2m x 4n
    const int cg   = lane >> 4, cl = lane & 15;

    const int nt = K >> 6;      // K-tiles (even)
    const int ni = nt >> 1;     // iterations

    auto stageA = [&](int t, int h) {
        ushort_t* dst = smem + (t & 1) * 32768 + h * 8192;
        const int k0 = t * 64;
        #pragma unroll
        for (int q = 0; q < 2; ++q) {
            const int slot = q * 512 + tid;
            const int r = slot >> 3, pc = slot & 7;
            const int col = (pc ^ (r & 7)) * 8;
            GLD_LDS16(&A[(long)(m0 + h * 128 + r) * lda + k0 + col], dst + slot * 8);
        }
    };
    auto stageB = [&](int t, int h) {
        ushort_t* dst = smem + (t & 1) * 32768 + 16384 + h * 8192;
        const int k0 = t * 64;
        #pragma unroll
        for (int q = 0; q < 2; ++q) {
            const int slot = q * 512 + tid;
            const int r = slot >> 3, pc = slot & 7;
            const int col = (pc ^ (r & 7)) * 8;
            GLD_LDS16(&B[(long)(n0 + h * 128 + r) * ldb + k0 + col], dst + slot * 8);
        }
    };

    // prologue: A(0), B(0), B(1) = 12 loads; retire oldest 8 (tile 0).
    stageA(0, 0); stageA(0, 1);
    stageB(0, 0); stageB(0, 1);
    stageB(1, 0); stageB(1, 1);
    asm volatile("s_waitcnt vmcnt(4)" ::: "memory");
    __builtin_amdgcn_s_barrier();

    f32x4 acc[8][4] = {};
    bf16x8 breg[4][2];

    for (int i = 0; i < ni; ++i) {
        const int te = 2 * i, to = te + 1;
        const bool nl = (i + 1 < ni);

        #pragma unroll
        for (int p = 0; p < 8; ++p) {
            const int t = (p < 4) ? te : to;
            const int q = p & 3;
            const ushort_t* Ar = smem + (t & 1) * 32768;
            const ushort_t* Br = Ar + 16384;

            if (q == 0) {
                #pragma unroll
                for (int nf = 0; nf < 4; ++nf) {
                    const int rb = wn * 64 + nf * 16 + cl;
                    #pragma unroll
                    for (int kk = 0; kk < 2; ++kk)
                        breg[nf][kk] = __builtin_bit_cast(bf16x8, *(const us8*)&Br[
                            rb * 64 + (((kk * 4 + cg) ^ (rb & 7)) * 8)]);
                }
            }
            bf16x8 af[2][2];
            #pragma unroll
            for (int mi = 0; mi < 2; ++mi) {
                const int ra = wm * 128 + q * 32 + mi * 16 + cl;
                #pragma unroll
                for (int kk = 0; kk < 2; ++kk)
                    af[mi][kk] = __builtin_bit_cast(bf16x8, *(const us8*)&Ar[
                        ra * 64 + (((kk * 4 + cg) ^ (ra & 7)) * 8)]);
            }

            if (p == 0)      { stageA(to, 0); }
            else if (p == 1) { stageA(to, 1); if (nl) stageB(te + 2, 0); }
            else if (p == 2) { if (nl) stageB(te + 2, 1); }
            else if (p == 4) { if (nl) stageA(te + 2, 0); }
            else if (p == 5) { if (nl) stageA(te + 2, 1); }
            else if (p == 6) { if (nl) stageB(to + 2, 0); }
            else if (p == 7) { if (nl) stageB(to + 2, 1); }

            __builtin_amdgcn_s_barrier();
            asm volatile("s_waitcnt lgkmcnt(0)" ::: "memory");
            __builtin_amdgcn_s_setprio(1);
            #pragma unroll
            for (int mi = 0; mi < 2; ++mi)
                #pragma unroll
                for (int nf = 0; nf < 4; ++nf)
                    #pragma unroll
                    for (int kk = 0; kk < 2; ++kk)
                        acc[q * 2 + mi][nf] = __builtin_amdgcn_mfma_f32_16x16x32_bf16(
                            af[mi][kk], breg[nf][kk], acc[q * 2 + mi][nf], 0, 0, 0);
            __builtin_amdgcn_s_setprio(0);

            if (p == 3) {
                if (nl) asm volatile("s_waitcnt vmcnt(4)" ::: "memory");
                else    asm volatile("s_waitcnt vmcnt(0)" ::: "memory");
            } else if (p == 7 && nl) {
                asm volatile("s_waitcnt vmcnt(4)" ::: "memory");
            }
            __builtin_amdgcn_s_barrier();
        }
    }

    if (EPI == EPI_F32) {
        // LDS-bounce coalesced epilogue. Chunk c covers mf in [4c, 4c+4):
        // global rows [m0+c*64, +64) U [m0+128+c*64, +64) -> lrow 0..127.
        // Swizzle: phys_col = col ^ (cg<<4); read side uses cg=(lrow>>2)&3.
        float* lds_f = (float*)smem;   // 128 KB
        #pragma unroll
        for (int c = 0; c < 2; ++c) {
            #pragma unroll
            for (int mf4 = 0; mf4 < 4; ++mf4) {
                #pragma unroll
                for (int nf = 0; nf < 4; ++nf) {
                    const int scol = (wn * 64 + nf * 16 + cl) ^ (cg << 4);
                    #pragma unroll
                    for (int r = 0; r < 4; ++r) {
                        const int lrow = wm * 64 + mf4 * 16 + cg * 4 + r;
                        lds_f[lrow * 256 + scol] = acc[c * 4 + mf4][nf][r];
                    }
                }
            }
            __builtin_amdgcn_s_barrier();
            #pragma unroll
            for (int rr = 0; rr < 16; ++rr) {
                const int lrow = wid * 16 + rr;
                const int rowg = m0 + (lrow >> 6) * 128 + c * 64 + (lrow & 63);
                const int lcol = (lane * 4) ^ ((((lrow >> 2) & 3)) << 4);
                const f32x4 v  = *(const f32x4*)&lds_f[lrow * 256 + lane * 4];
                *(f32x4*)&((float*)Cv)[(long)rowg * ldc + n0 + lcol] = v;
            }
            if (c == 0) __builtin_amdgcn_s_barrier();
        }
        return;
    }

    const int rb = m0 + wm * 128 + cg * 4;
    const int cb = n0 + wn * 64 + cl;

    #pragma unroll
    for (int mf = 0; mf < 8; ++mf) {
        #pragma unroll
        for (int nf = 0; nf < 4; ++nf) {
            const int colg = cb + nf * 16;
            #pragma unroll
            for (int r = 0; r < 4; ++r) {
                const int  rowg = rb + mf * 16 + r;
                const long off  = (long)rowg * ldc + colg;
                const float val = acc[mf][nf][r];
                if (EPI == EPI_GELU) {
                    float g = 0.5f * val * (1.0f + erff(val * 0.70710678118654752f));
                    ((ushort_t*)Cv)[off] = f2bf(g);
                } else {
                    ((ushort_t*)Cv)[off] = f2bf(val);
                }
            }
        }
    }
}

// ---------------------------------------------------------------------------
// gemm8p (round-3 structure, kept for QKV / FFN-down): 128x256, BK=64,
// triple-buffered, 4-phase, counted vmcnt(6) at tile boundary.
// ---------------------------------------------------------------------------
template<int EPI>
__global__ __launch_bounds__(512)
void gemm8p(const ushort_t* __restrict__ A, const ushort_t* __restrict__ B,
            void* __restrict__ Cv, int mt, int K, int lda, int ldb, int ldc,
            long bsA, long bsB, long bsC)
{
    extern __shared__ ushort_t smem[];   // 3 bufs x (A 8192 + B 16384) ushorts

    const int nwg  = gridDim.x;
    const int orig = blockIdx.x;
    int wgid = orig;
    if (nwg >= 8) {
        const int q = nwg >> 3, r = nwg & 7;
        const int xcd = orig & 7, i = orig >> 3;
        wgid = (xcd < r ? xcd * (q + 1) : r * (q + 1) + (xcd - r) * q) + i;
    }
    const int m0 = (wgid % mt) * 128;
    const int n0 = (wgid / mt) * 256;

    A += (long)blockIdx.z * bsA;
    B += (long)blockIdx.z * bsB;

    const int tid  = threadIdx.x;
    const int lane = tid & 63;
    const int wid  = tid >> 6;
    const int wm   = wid >> 2, wn = wid & 3;
    const int cg   = lane >> 4, cl = lane & 15;
    const int lr   = lane >> 3;
    const int lcc  = (lane & 7) * 8;

    const int nt = K >> 6;

    auto stage = [&](int kt, int buf, int part) {
        ushort_t* base = smem + buf * 24576;
        const int k0 = kt * 64;
        if (part < 2) {
            const int rbase = part * 64 + wid * 8;
            const int row   = rbase + lr;
            const int col   = lcc ^ ((row & 7) << 3);
            GLD_LDS16(&A[(long)(m0 + row) * lda + k0 + col], base + rbase * 64);
        } else {
            const int rbase = (part - 2) * 64 + wid * 8;
            const int row   = rbase + lr;
            const int col   = lcc ^ ((row & 7) << 3);
            GLD_LDS16(&B[(long)(n0 + row) * ldb + k0 + col],
                      base + 8192 + rbase * 64);
        }
    };

    #pragma unroll
    for (int p = 0; p < 6; ++p) stage(0, 0, p);
    #pragma unroll
    for (int p = 0; p < 6; ++p) stage(1, 1, p);
    asm volatile("s_waitcnt vmcnt(6)" ::: "memory");
    __builtin_amdgcn_s_barrier();

    f32x4 acc[4][4] = {};

    for (int t = 0; t < nt; ++t) {
        const ushort_t* Aq = smem + (t % 3) * 24576;
        const ushort_t* Bq = Aq + 8192;
        const int sbuf = (t + 2) % 3;
        const bool do_stage = (t + 2 < nt);

        bf16x8 breg[4][2];
        #pragma unroll
        for (int p = 0; p < 4; ++p) {
            const int rowA = wm * 64 + p * 16 + cl;
            bf16x8 aA[2];
            #pragma unroll
            for (int kk = 0; kk < 2; ++kk)
                aA[kk] = __builtin_bit_cast(bf16x8, *(const us8*)&Aq[
                    rowA * 64 + ((kk * 32 + cg * 8) ^ ((rowA & 7) << 3))]);
            if (p == 0) {
                #pragma unroll
                for (int nj = 0; nj < 4; ++nj) {
                    const int rowB = wn * 64 + nj * 16 + cl;
                    #pragma unroll
                    for (int kk = 0; kk < 2; ++kk)
                        breg[nj][kk] = __builtin_bit_cast(bf16x8, *(const us8*)&Bq[
                            rowB * 64 + ((kk * 32 + cg * 8) ^ ((rowB & 7) << 3))]);
                }
            }
            if (do_stage) {
                if (p == 0)      { stage(t + 2, sbuf, 0); stage(t + 2, sbuf, 1); }
                else if (p == 1) { stage(t + 2, sbuf, 2); stage(t + 2, sbuf, 3); }
                else if (p == 2) { stage(t + 2, sbuf, 4); }
                else             { stage(t + 2, sbuf, 5); }
            }
            __builtin_amdgcn_s_setprio(1);
            #pragma unroll
            for (int nj = 0; nj < 4; ++nj)
                #pragma unroll
                for (int kk = 0; kk < 2; ++kk)
                    acc[p][nj] = __builtin_amdgcn_mfma_f32_16x16x32_bf16(
                        aA[kk], breg[nj][kk], acc[p][nj], 0, 0, 0);
            __builtin_amdgcn_s_setprio(0);
            __builtin_amdgcn_s_barrier();
        }
        if (do_stage) asm volatile("s_waitcnt vmcnt(6)" ::: "memory");
        else          asm volatile("s_waitcnt vmcnt(0)" ::: "memory");
        __builtin_amdgcn_s_barrier();
    }

    const int rb = m0 + wm * 64 + cg * 4;
    const int cb = n0 + wn * 64 + cl;

    #pragma unroll
    for (int mi = 0; mi < 4; ++mi) {
        #pragma unroll
        for (int nj = 0; nj < 4; ++nj) {
            const int colg = cb + nj * 16;
            if (EPI == EPI_QKV) {
                ushort_t* Q = (ushort_t*)Cv;
                if (n0 < 1024) {
                    #pragma unroll
                    for (int r = 0; r < 4; ++r)
                        Q[(long)(rb + mi * 16 + r) * 1024 + colg] = f2bf(acc[mi][nj][r]);
                } else if (n0 < 2048) {
                    #pragma unroll
                    for (int r = 0; r < 4; ++r)
                        Q[2097152 + (long)(rb + mi * 16 + r) * 1024 + (colg - 1024)] =
                            f2bf(acc[mi][nj][r]);
                } else {
                    ushort_t* Vt = Q + 4194304;
                    const int rowg = rb + mi * 16;
                    const long boff = (long)(rowg >> 10) * 1048576;
                    us4 o4;
                    #pragma unroll
                    for (int r = 0; r < 4; ++r) o4[r] = f2bf(acc[mi][nj][r]);
                    *(us4*)&Vt[boff + (long)(colg - 2048) * 1024 + (rowg & 1023)] = o4;
                }
            } else {
                #pragma unroll
                for (int r = 0; r < 4; ++r) {
                    const int  rowg = rb + mi * 16 + r;
                    const long off  = (long)rowg * ldc + colg;
                    const float val = acc[mi][nj][r];
                    if (EPI == EPI_F32) {
                        ((float*)Cv)[off] = val;
                    } else if (EPI == EPI_GELU) {
                        float g = 0.5f * val * (1.0f + erff(val * 0.70710678118654752f));
                        ((ushort_t*)Cv)[off] = f2bf(g);
                    } else if (EPI == EPI_ATOM) {
                        atomicAdd(&((float*)Cv)[off], val);
                    } else {
                        ((ushort_t*)Cv)[off] = f2bf(val);
                    }
                }
            }
        }
    }
}

// ---------------------------------------------------------------------------
// m97-style 64-row GEMM kept for Wo (full-fill 256-block grid, K=1024).
// ---------------------------------------------------------------------------
template<int EPI, int MT>
__global__ __launch_bounds__(256)
void gemm128(const ushort_t* __restrict__ A, const ushort_t* __restrict__ B,
             void* __restrict__ Cv, int K, int lda, int ldb, int ldc)
{
    const int m0 = blockIdx.x * (MT * 32);
    const int n0 = blockIdx.y * 128;

    __shared__ __align__(16) ushort_t As[MT * 32][64];
    __shared__ __align__(16) ushort_t Bs[128][64];

    const int tid  = threadIdx.x;
    const int lane = tid & 63;
    const int wid  = tid >> 6;
    const int wr   = wid >> 1, wc = wid & 1;
    const int lr   = lane >> 3;
    const int lc   = (lane & 7) * 8;
    const int cg   = lane >> 4;
    const int cl   = lane & 15;

    f32x4 acc[MT][4] = {};

    for (int k0 = 0; k0 < K; k0 += 64) {
        #pragma unroll
        for (int j = 0; j < MT; ++j) {
            const int r = wid * (8 * MT) + j * 8;
            GLD_LDS16(&A[(long)(m0 + r + lr) * lda + k0 + lc], &As[r][0]);
        }
        #pragma unroll
        for (int j = 0; j < 4; ++j) {
            const int r = wid * 32 + j * 8;
            GLD_LDS16(&B[(long)(n0 + r + lr) * ldb + k0 + lc], &Bs[r][0]);
        }
        __syncthreads();
        #pragma unroll
        for (int kk = 0; kk < 2; ++kk) {
            const int krd = kk * 32 + cg * 8;
            bf16x8 af[MT], bfr[4];
            #pragma unroll
            for (int mi = 0; mi < MT; ++mi)
                af[mi] = __builtin_bit_cast(bf16x8,
                    *(const us8*)&As[wr * (MT * 16) + mi * 16 + cl][krd]);
            #pragma unroll
            for (int nj = 0; nj < 4; ++nj)
                bfr[nj] = __builtin_bit_cast(bf16x8,
                    *(const us8*)&Bs[wc * 64 + nj * 16 + cl][krd]);
            #pragma unroll
            for (int mi = 0; mi < MT; ++mi)
                #pragma unroll
                for (int nj = 0; nj < 4; ++nj)
                    acc[mi][nj] = __builtin_amdgcn_mfma_f32_16x16x32_bf16(
                        af[mi], bfr[nj], acc[mi][nj], 0, 0, 0);
        }
        __syncthreads();
    }

    const int rb = m0 + wr * (MT * 16) + cg * 4;
    const int cb = n0 + wc * 64 + cl;

    #pragma unroll
    for (int mi = 0; mi < MT; ++mi)
        #pragma unroll
        for (int nj = 0; nj < 4; ++nj)
            #pragma unroll
            for (int r = 0; r < 4; ++r) {
                const long off = (long)(rb + mi * 16 + r) * ldc + cb + nj * 16;
                const float val = acc[mi][nj][r];
                if (EPI == EPI_ADDF32)      ((float*)Cv)[off] += val;
                else if (EPI == EPI_F32)    ((float*)Cv)[off] = val;
                else                        ((ushort_t*)Cv)[off] = f2bf(val);
            }
}

// ---------------------------------------------------------------------------
// Fused causal flash attention v2 (log2 softmax, defer-max, hoisted V loads).
// ---------------------------------------------------------------------------
#define ATT_SCL 0.1803368805f   // 0.125 * log2(e)
#define ATT_THR 12.0f

__global__ __launch_bounds__(256)
void flash_attn(const ushort_t* __restrict__ qb, const ushort_t* __restrict__ kb,
                const ushort_t* __restrict__ vT, ushort_t* __restrict__ ob)
{
    const int qt = gridDim.x - 1 - blockIdx.x;
    const int hh = blockIdx.y;
    const int bb = blockIdx.z;
    const int lane = threadIdx.x & 63;
    const int w    = threadIdx.x >> 6;
    const int cg   = lane >> 4;
    const int cl   = lane & 15;

    __shared__ __align__(16) ushort_t P_lds[4][16][72];

    const int q0 = qt * 64;
    const long tokQ = (long)bb * 1024 + q0 + w * 16 + cl;

    bf16x8 qf[2];
    #pragma unroll
    for (int kk = 0; kk < 2; ++kk)
        qf[kk] = __builtin_bit_cast(bf16x8,
            *(const us8*)&qb[tokQ * 1024 + hh * 64 + kk * 32 + cg * 8]);

    const ushort_t* kbase = kb + (long)bb * 1048576 + hh * 64;
    const ushort_t* vbase = vT + (long)bb * 1048576 + (long)hh * 65536;

    f32x4 o[4] = {};
    float m4[4], l4[4];
    #pragma unroll
    for (int r = 0; r < 4; ++r) { m4[r] = -1e30f; l4[r] = 0.0f; }

    for (int tt = 0; tt <= qt; ++tt) {
        const int t0 = tt * 64;
        f32x4 s[4] = {};
        __builtin_amdgcn_s_setprio(1);
        #pragma unroll
        for (int nj = 0; nj < 4; ++nj) {
            const ushort_t* kp = kbase + (long)(t0 + nj * 16 + cl) * 1024 + cg * 8;
            bf16x8 kf0 = __builtin_bit_cast(bf16x8, *(const us8*)kp);
            bf16x8 kf1 = __builtin_bit_cast(bf16x8, *(const us8*)(kp + 32));
            s[nj] = __builtin_amdgcn_mfma_f32_16x16x32_bf16(qf[0], kf0, s[nj], 0, 0, 0);
            s[nj] = __builtin_amdgcn_mfma_f32_16x16x32_bf16(qf[1], kf1, s[nj], 0, 0, 0);
        }
        __builtin_amdgcn_s_setprio(0);

        bf16x8 vreg[4][2];
        #pragma unroll
        for (int nj = 0; nj < 4; ++nj) {
            const ushort_t* vp = vbase + (long)(nj * 16 + cl) * 1024 + t0 + cg * 8;
            vreg[nj][0] = __builtin_bit_cast(bf16x8, *(const us8*)vp);
            vreg[nj][1] = __builtin_bit_cast(bf16x8, *(const us8*)(vp + 32));
        }

        const bool diag = (tt == qt);
        float pm[4] = {-3e30f, -3e30f, -3e30f, -3e30f};
        #pragma unroll
        for (int nj = 0; nj < 4; ++nj)
            #pragma unroll
            for (int r = 0; r < 4; ++r) {
                float v = s[nj][r] * ATT_SCL;
                if (diag && (t0 + nj * 16 + cl) > (q0 + w * 16 + cg * 4 + r))
                    v = -3e30f;
                s[nj][r] = v;
                pm[r] = fmaxf(pm[r], v);
            }
        #pragma unroll
        for (int r = 0; r < 4; ++r)
            #pragma unroll
            for (int msk = 1; msk < 16; msk <<= 1)
                pm[r] = fmaxf(pm[r], __shfl_xor(pm[r], msk));

        const bool grow = (pm[0] > m4[0] + ATT_THR) || (pm[1] > m4[1] + ATT_THR)
                       || (pm[2] > m4[2] + ATT_THR) || (pm[3] > m4[3] + ATT_THR);
        if (__any(grow)) {
            #pragma unroll
            for (int r = 0; r < 4; ++r) {
                const float mn = fmaxf(m4[r], pm[r]);
                const float al = __builtin_amdgcn_exp2f(m4[r] - mn);
                m4[r] = mn;
                l4[r] *= al;
                #pragma unroll
                for (int nj = 0; nj < 4; ++nj) o[nj][r] *= al;
            }
        }
        float ps[4] = {0.0f, 0.0f, 0.0f, 0.0f};
        #pragma unroll
        for (int nj = 0; nj < 4; ++nj)
            #pragma unroll
            for (int r = 0; r < 4; ++r) {
                const float p = __builtin_amdgcn_exp2f(s[nj][r] - m4[r]);
                s[nj][r] = p;
                ps[r] += p;
            }
        #pragma unroll
        for (int r = 0; r < 4; ++r) {
            #pragma unroll
            for (int msk = 1; msk < 16; msk <<= 1)
                ps[r] += __shfl_xor(ps[r], msk);
            l4[r] += ps[r];
        }
        #pragma unroll
        for (int nj = 0; nj < 4; ++nj)
            #pragma unroll
            for (int r = 0; r < 4; ++r)
                P_lds[w][cg * 4 + r][nj * 16 + cl] = bf16u(s[nj][r]);
        asm volatile("s_waitcnt lgkmcnt(0)" ::: "memory");
        __builtin_amdgcn_sched_barrier(0);
        bf16x8 pa[2];
        #pragma unroll
        for (int kk = 0; kk < 2; ++kk)
            pa[kk] = __builtin_bit_cast(bf16x8,
                *(const us8*)&P_lds[w][cl][kk * 32 + cg * 8]);
        __builtin_amdgcn_s_setprio(1);
        #pragma unroll
        for (int nj = 0; nj < 4; ++nj) {
            o[nj] = __builtin_amdgcn_mfma_f32_16x16x32_bf16(pa[0], vreg[nj][0], o[nj], 0, 0, 0);
            o[nj] = __builtin_amdgcn_mfma_f32_16x16x32_bf16(pa[1], vreg[nj][1], o[nj], 0, 0, 0);
        }
        __builtin_amdgcn_s_setprio(0);
    }

    #pragma unroll
    for (int r = 0; r < 4; ++r) {
        const float inv = 1.0f / l4[r];
        const long tok = (long)bb * 1024 + q0 + w * 16 + cg * 4 + r;
        #pragma unroll
        for (int nj = 0; nj < 4; ++nj)
            ob[tok * 1024 + hh * 64 + nj * 16 + cl] = bf16u(o[nj][r] * inv);
    }
}

// ---------------------------------------------------------------------------
// Transpose + f32->bf16, vectorized writes: tile 32 n x 128 k, block (32,8).
// LDS f32 [32][132] (pad -> conflict-light, 16B-aligned rows). Writes us4
// (256B wave runs, 4x fewer store instrs than scalar us).
// ---------------------------------------------------------------------------
__global__ __launch_bounds__(256)
void transpose_conv(const float* __restrict__ in, ushort_t* __restrict__ out,
                    long ldin, long ldout, long bsin, long bsout,
                    long bsout_hi, int zmod)
{
    __shared__ float tile[32][132];
    const int tx = threadIdx.x, ty = threadIdx.y;
    const long bin  = (long)blockIdx.z * bsin;
    const long bout = (long)(blockIdx.z % zmod) * bsout
                    + (long)(blockIdx.z / zmod) * bsout_hi;
    const int n0 = blockIdx.x * 32, k0 = blockIdx.y * 128;
    #pragma unroll
    for (int i = 0; i < 16; ++i)
        tile[tx][ty + i * 8] = in[bin + (long)(k0 + ty + i * 8) * ldin + n0 + tx];
    __syncthreads();
    #pragma unroll
    for (int i = 0; i < 4; ++i) {
        const int n = ty + i * 8;
        const f32x4 v = *(const f32x4*)&tile[n][tx * 4];
        us4 o4;
        o4[0] = bf16u(v[0]); o4[1] = bf16u(v[1]);
        o4[2] = bf16u(v[2]); o4[3] = bf16u(v[3]);
        *(us4*)&out[bout + (long)(n0 + n) * ldout + k0 + tx * 4] = o4;
    }
}

// ---------------------------------------------------------------------------
__global__ __launch_bounds__(256)
void embed_kernel(const int* __restrict__ x, const float* __restrict__ emb,
                  const float* __restrict__ pos, float* __restrict__ h)
{
    const int row = blockIdx.x, tid = threadIdx.x;
    const int s = row & 1023;
    const int idx = x[row];
    const float4 e = ((const float4*)(emb + (long)idx * 1024))[tid];
    const float4 p = ((const float4*)(pos + (long)s * 1024))[tid];
    float4 o; o.x = e.x + p.x; o.y = e.y + p.y; o.z = e.z + p.z; o.w = e.w + p.w;
    ((float4*)(h + (long)row * 1024))[tid] = o;
}

// ---------------------------------------------------------------------------
__global__ __launch_bounds__(256)
void ln_kernel(const float* __restrict__ x, const float* __restrict__ g,
               const float* __restrict__ b, ushort_t* __restrict__ z)
{
    const int row = blockIdx.x, tid = threadIdx.x;
    const float4 v = ((const float4*)(x + (long)row * 1024))[tid];
    float s  = v.x + v.y + v.z + v.w;
    float sq = v.x * v.x + v.y * v.y + v.z * v.z + v.w * v.w;
    #pragma unroll
    for (int o = 32; o > 0; o >>= 1) { s += __shfl_down(s, o); sq += __shfl_down(sq, o); }
    __shared__ float ls[4], lq[4];
    if ((tid & 63) == 0) { ls[tid >> 6] = s; lq[tid >> 6] = sq; }
    __syncthreads();
    s  = ls[0] + ls[1] + ls[2] + ls[3];
    sq = lq[0] + lq[1] + lq[2] + lq[3];
    const float mu   = s * (1.0f / 1024.0f);
    const float var  = sq * (1.0f / 1024.0f) - mu * mu;
    const float rstd = rsqrtf(var + LN_EPS);
    const float4 gg = ((const float4*)g)[tid];
    const float4 bb = ((const float4*)b)[tid];
    us4 o4;
    o4[0] = f2bf((v.x - mu) * rstd * gg.x + bb.x);
    o4[1] = f2bf((v.y - mu) * rstd * gg.y + bb.y);
    o4[2] = f2bf((v.z - mu) * rstd * gg.z + bb.z);
    o4[3] = f2bf((v.w - mu) * rstd * gg.w + bb.w);
    *(us4*)(z + (long)row * 1024 + tid * 4) = o4;
}

// ---------------------------------------------------------------------------
extern "C" void kernel_launch(void* const* d_in, const int* in_sizes, int n_in,
                              void* d_out, int out_size, void* d_ws, size_t ws_size,
                              hipStream_t stream)
{
    const int*   x   = (const int*)  d_in[0];
    const float* emb = (const float*)d_in[1];
    const float* pos = (const float*)d_in[2];
    const float* Wq  = (const float*)d_in[3];
    const float* Wk  = (const float*)d_in[4];
    const float* Wv  = (const float*)d_in[5];
    const float* Wo  = (const float*)d_in[6];
    const float* g1  = (const float*)d_in[7];
    const float* b1  = (const float*)d_in[8];
    const float* g2  = (const float*)d_in[9];
    const float* b2  = (const float*)d_in[10];
    const float* W1  = (const float*)d_in[11];
    const float* W2  = (const float*)d_in[12];
    const float* gf  = (const float*)d_in[13];
    const float* bfp = (const float*)d_in[14];
    const float* Wf  = (const float*)d_in[15];
    float* out = (float*)d_out;

    char* ws = (char*)d_ws;
    size_t off = 0;
    auto alloc = [&](size_t bytes) {
        char* p = ws + off;
        off = (off + bytes + 255) & ~(size_t)255;
        return p;
    };
    ushort_t* WqkvT = (ushort_t*)alloc(4UL * 3145728 * 2);   // [L][3][1024][1024]
    ushort_t* WoT   = (ushort_t*)alloc(4UL * 1048576 * 2);
    ushort_t* W1T   = (ushort_t*)alloc(4UL * 6291456 * 2);
    ushort_t* W2T   = (ushort_t*)alloc(4UL * 6291456 * 2);
    ushort_t* WfT   = (ushort_t*)alloc(32768000UL * 2);
    float*    h     = (float*)   alloc(2048UL * 1024 * 4);
    ushort_t* z     = (ushort_t*)alloc(2048UL * 1024 * 2);
    ushort_t* qb    = (ushort_t*)alloc(3UL * 2048 * 1024 * 2); // q | k | vT
    ushort_t* kb    = qb + 2097152;
    ushort_t* vT    = qb + 4194304;
    ushort_t* ob    = (ushort_t*)alloc(2048UL * 1024 * 2);
    ushort_t* ub    = (ushort_t*)alloc(2048UL * 6144 * 2);
    (void)ws_size; (void)in_sizes; (void)n_in; (void)out_size;

    const int LDS8P = 2 * 32768 * 2;   // 128 KiB for gemm8ph
    const int LDS3B = 3 * 49152;       // 144 KiB for gemm8p
    hipFuncSetAttribute((const void*)&gemm8ph<EPI_F32>,
                        hipFuncAttributeMaxDynamicSharedMemorySize, LDS8P);
    hipFuncSetAttribute((const void*)&gemm8ph<EPI_GELU>,
                        hipFuncAttributeMaxDynamicSharedMemorySize, LDS8P);
    hipFuncSetAttribute((const void*)&gemm8p<EPI_QKV>,
                        hipFuncAttributeMaxDynamicSharedMemorySize, LDS3B);
    hipFuncSetAttribute((const void*)&gemm8p<EPI_ATOM>,
                        hipFuncAttributeMaxDynamicSharedMemorySize, LDS3B);

    const dim3 tb(32, 8);
    // q/k/v -> fused [L][3][1024 out][1024 K] (B^T layout)
    transpose_conv<<<dim3(2,   8, 64), tb, 0, stream>>>(Wq, WqkvT,           64, 1024, 65536, 65536, 3145728, 16);
    transpose_conv<<<dim3(2,   8, 64), tb, 0, stream>>>(Wk, WqkvT + 1048576, 64, 1024, 65536, 65536, 3145728, 16);
    transpose_conv<<<dim3(2,   8, 64), tb, 0, stream>>>(Wv, WqkvT + 2097152, 64, 1024, 65536, 65536, 3145728, 16);
    transpose_conv<<<dim3(32,  8,  4), tb, 0, stream>>>(Wo, WoT, 1024,  1024, 1048576, 1048576, 0, 4);
    transpose_conv<<<dim3(192, 8,  4), tb, 0, stream>>>(W1, W1T, 6144,  1024, 6291456, 6291456, 0, 4);
    transpose_conv<<<dim3(32, 48,  4), tb, 0, stream>>>(W2, W2T, 1024,  6144, 6291456, 6291456, 0, 4);
    transpose_conv<<<dim3(1000,8,  1), tb, 0, stream>>>(Wf, WfT, 32000, 1024, 0,       0,       0, 1);

    embed_kernel<<<2048, 256, 0, stream>>>(x, emb, pos, h);

    for (int l = 0; l < 4; ++l) {
        const size_t wff = (size_t)l * 6291456;

        ln_kernel<<<2048, 256, 0, stream>>>(h, g1 + l * 1024, b1 + l * 1024, z);

        // fused QKV: [2048,3072] = z @ WqkvT^T   (192 blocks, r3 structure)
        gemm8p<EPI_QKV><<<dim3(16 * 12), 512, LDS3B, stream>>>(
            z, WqkvT + (size_t)l * 3145728, qb, 16, 1024, 1024, 1024, 1024, 0, 0, 0);

        flash_attn<<<dim3(16, 16, 2), 256, 0, stream>>>(qb, kb, vT, ob);

        // h += o @ Wo  (m97 kernel, full-fill 256-block grid)
        gemm128<EPI_ADDF32, 2><<<dim3(32, 8), 256, 0, stream>>>(
            ob, WoT + (size_t)l * 1048576, h, 1024, 1024, 1024, 1024);

        ln_kernel<<<2048, 256, 0, stream>>>(h, g2 + l * 1024, b2 + l * 1024, z);

        // u = gelu(z @ W1)   (192 blocks, 8-phase)
        gemm8ph<EPI_GELU><<<dim3(8 * 24), 512, LDS8P, stream>>>(
            z, W1T + wff, ub, 8, 1024, 1024, 1024, 6144);
        // h += u @ W2, K split 4 ways, atomic f32 accumulate (256 blocks, r3)
        gemm8p<EPI_ATOM><<<dim3(16 * 4, 1, 4), 512, LDS3B, stream>>>(
            ub, W2T + wff, h, 16, 1536, 6144, 6144, 1024, 1536, 1536, 0);
    }

    ln_kernel<<<2048, 256, 0, stream>>>(h, gf, bfp, z);
    // logits = z @ Wf -> f32 [2048, 32000]   (1000 blocks, 8-phase, bounce epi)
    gemm8ph<EPI_F32><<<dim3(8 * 125), 512, LDS8P, stream>>>(
        z, WfT, out, 8, 1024, 1024, 1024, 32000);
}

// Round 15
// 1109.772 us; speedup vs baseline: 1.0528x; 1.0528x over previous
//
#include <hip/hip_runtime.h>
#include <hip/hip_bf16.h>
#include <math.h>

// GPT forward, bf16 MFMA GEMMs + f32 residual stream.
// Dims: L=4, B=2, S=1024, E=1024, H=16, HD=64, FF=6144, V=32000, tokens T=2048.

typedef unsigned short ushort_t;
typedef unsigned short us8 __attribute__((ext_vector_type(8)));
typedef unsigned short us4 __attribute__((ext_vector_type(4)));
typedef __bf16 bf16x8 __attribute__((ext_vector_type(8)));
typedef float f32x4 __attribute__((ext_vector_type(4)));

#define LN_EPS 1e-5f

__device__ inline ushort_t f2bf(float f) {
    union { float f; unsigned u; } v; v.f = f;
    unsigned r = v.u + 0x7FFFu + ((v.u >> 16) & 1u);   // RNE
    return (ushort_t)(r >> 16);
}

__device__ inline ushort_t bf16u(float f) {   // hw cvt
    __hip_bfloat16 h = __float2bfloat16(f);
    return *(ushort_t*)&h;
}

#define GLD_LDS16(gp, lp)                                                  \
    __builtin_amdgcn_global_load_lds(                                      \
        (const __attribute__((address_space(1))) unsigned int*)(gp),       \
        (__attribute__((address_space(3))) unsigned int*)(lp), 16, 0, 0)

enum { EPI_F32 = 0, EPI_BF16 = 1, EPI_ADDF32 = 2, EPI_GELU = 3, EPI_TBF16 = 4,
       EPI_ATOM = 5, EPI_QKV = 6 };

// ---------------------------------------------------------------------------
// gemm8ph: 8-phase 256x256 GEMM (r7 v1 schedule + r14 bounce epilogue).
// ---------------------------------------------------------------------------
template<int EPI>
__global__ __launch_bounds__(512)
void gemm8ph(const ushort_t* __restrict__ A, const ushort_t* __restrict__ B,
             void* __restrict__ Cv, int mt, int K, int lda, int ldb, int ldc)
{
    extern __shared__ ushort_t smem[];   // 2 x (16384 A + 16384 B) ushorts

    const int nwg  = gridDim.x;
    const int orig = blockIdx.x;
    int wgid = orig;
    if (nwg >= 8) {
        const int q = nwg >> 3, r = nwg & 7;
        const int xcd = orig & 7, i = orig >> 3;
        wgid = (xcd < r ? xcd * (q + 1) : r * (q + 1) + (xcd - r) * q) + i;
    }
    const int m0 = (wgid % mt) * 256;
    const int n0 = (wgid / mt) * 256;

    const int tid  = threadIdx.x;
    const int lane = tid & 63;
    const int wid  = tid >> 6;
    const int wm   = wid >> 2, wn = wid & 3;   // 2m x 4n
    const int cg   = lane >> 4, cl = lane & 15;

    const int nt = K >> 6;      // K-tiles (even)
    const int ni = nt >> 1;     // iterations

    auto stageA = [&](int t, int h) {
        ushort_t* dst = smem + (t & 1) * 32768 + h * 8192;
        const int k0 = t * 64;
        #pragma unroll
        for (int q = 0; q < 2; ++q) {
            const int slot = q * 512 + tid;
            const int r = slot >> 3, pc = slot & 7;
            const int col = (pc ^ (r & 7)) * 8;
            GLD_LDS16(&A[(long)(m0 + h * 128 + r) * lda + k0 + col], dst + slot * 8);
        }
    };
    auto stageB = [&](int t, int h) {
        ushort_t* dst = smem + (t & 1) * 32768 + 16384 + h * 8192;
        const int k0 = t * 64;
        #pragma unroll
        for (int q = 0; q < 2; ++q) {
            const int slot = q * 512 + tid;
            const int r = slot >> 3, pc = slot & 7;
            const int col = (pc ^ (r & 7)) * 8;
            GLD_LDS16(&B[(long)(n0 + h * 128 + r) * ldb + k0 + col], dst + slot * 8);
        }
    };

    // prologue: A(0), B(0), B(1) = 12 loads; retire oldest 8 (tile 0).
    stageA(0, 0); stageA(0, 1);
    stageB(0, 0); stageB(0, 1);
    stageB(1, 0); stageB(1, 1);
    asm volatile("s_waitcnt vmcnt(4)" ::: "memory");
    __builtin_amdgcn_s_barrier();

    f32x4 acc[8][4] = {};
    bf16x8 breg[4][2];

    for (int i = 0; i < ni; ++i) {
        const int te = 2 * i, to = te + 1;
        const bool nl = (i + 1 < ni);

        #pragma unroll
        for (int p = 0; p < 8; ++p) {
            const int t = (p < 4) ? te : to;
            const int q = p & 3;
            const ushort_t* Ar = smem + (t & 1) * 32768;
            const ushort_t* Br = Ar + 16384;

            if (q == 0) {
                #pragma unroll
                for (int nf = 0; nf < 4; ++nf) {
                    const int rb = wn * 64 + nf * 16 + cl;
                    #pragma unroll
                    for (int kk = 0; kk < 2; ++kk)
                        breg[nf][kk] = __builtin_bit_cast(bf16x8, *(const us8*)&Br[
                            rb * 64 + (((kk * 4 + cg) ^ (rb & 7)) * 8)]);
                }
            }
            bf16x8 af[2][2];
            #pragma unroll
            for (int mi = 0; mi < 2; ++mi) {
                const int ra = wm * 128 + q * 32 + mi * 16 + cl;
                #pragma unroll
                for (int kk = 0; kk < 2; ++kk)
                    af[mi][kk] = __builtin_bit_cast(bf16x8, *(const us8*)&Ar[
                        ra * 64 + (((kk * 4 + cg) ^ (ra & 7)) * 8)]);
            }

            if (p == 0)      { stageA(to, 0); }
            else if (p == 1) { stageA(to, 1); if (nl) stageB(te + 2, 0); }
            else if (p == 2) { if (nl) stageB(te + 2, 1); }
            else if (p == 4) { if (nl) stageA(te + 2, 0); }
            else if (p == 5) { if (nl) stageA(te + 2, 1); }
            else if (p == 6) { if (nl) stageB(to + 2, 0); }
            else if (p == 7) { if (nl) stageB(to + 2, 1); }

            __builtin_amdgcn_s_barrier();
            asm volatile("s_waitcnt lgkmcnt(0)" ::: "memory");
            __builtin_amdgcn_s_setprio(1);
            #pragma unroll
            for (int mi = 0; mi < 2; ++mi)
                #pragma unroll
                for (int nf = 0; nf < 4; ++nf)
                    #pragma unroll
                    for (int kk = 0; kk < 2; ++kk)
                        acc[q * 2 + mi][nf] = __builtin_amdgcn_mfma_f32_16x16x32_bf16(
                            af[mi][kk], breg[nf][kk], acc[q * 2 + mi][nf], 0, 0, 0);
            __builtin_amdgcn_s_setprio(0);

            if (p == 3) {
                if (nl) asm volatile("s_waitcnt vmcnt(4)" ::: "memory");
                else    asm volatile("s_waitcnt vmcnt(0)" ::: "memory");
            } else if (p == 7 && nl) {
                asm volatile("s_waitcnt vmcnt(4)" ::: "memory");
            }
            __builtin_amdgcn_s_barrier();
        }
    }

    if (EPI == EPI_F32) {
        // LDS-bounce coalesced epilogue (r14).
        float* lds_f = (float*)smem;
        #pragma unroll
        for (int c = 0; c < 2; ++c) {
            #pragma unroll
            for (int mf4 = 0; mf4 < 4; ++mf4) {
                #pragma unroll
                for (int nf = 0; nf < 4; ++nf) {
                    const int scol = (wn * 64 + nf * 16 + cl) ^ (cg << 4);
                    #pragma unroll
                    for (int r = 0; r < 4; ++r) {
                        const int lrow = wm * 64 + mf4 * 16 + cg * 4 + r;
                        lds_f[lrow * 256 + scol] = acc[c * 4 + mf4][nf][r];
                    }
                }
            }
            __builtin_amdgcn_s_barrier();
            #pragma unroll
            for (int rr = 0; rr < 16; ++rr) {
                const int lrow = wid * 16 + rr;
                const int rowg = m0 + (lrow >> 6) * 128 + c * 64 + (lrow & 63);
                const int lcol = (lane * 4) ^ ((((lrow >> 2) & 3)) << 4);
                const f32x4 v  = *(const f32x4*)&lds_f[lrow * 256 + lane * 4];
                *(f32x4*)&((float*)Cv)[(long)rowg * ldc + n0 + lcol] = v;
            }
            if (c == 0) __builtin_amdgcn_s_barrier();
        }
        return;
    }

    const int rb = m0 + wm * 128 + cg * 4;
    const int cb = n0 + wn * 64 + cl;

    #pragma unroll
    for (int mf = 0; mf < 8; ++mf) {
        #pragma unroll
        for (int nf = 0; nf < 4; ++nf) {
            const int colg = cb + nf * 16;
            #pragma unroll
            for (int r = 0; r < 4; ++r) {
                const int  rowg = rb + mf * 16 + r;
                const long off  = (long)rowg * ldc + colg;
                const float val = acc[mf][nf][r];
                if (EPI == EPI_GELU) {
                    float g = 0.5f * val * (1.0f + erff(val * 0.70710678118654752f));
                    ((ushort_t*)Cv)[off] = f2bf(g);
                } else {
                    ((ushort_t*)Cv)[off] = f2bf(val);
                }
            }
        }
    }
}

// ---------------------------------------------------------------------------
// gemm8p (round-3 structure, QKV / FFN-down): 128x256, BK=64, triple-buffered,
// 4-phase, counted vmcnt(6). EPI_F32 now supports per-z partial output (bsC).
// ---------------------------------------------------------------------------
template<int EPI>
__global__ __launch_bounds__(512)
void gemm8p(const ushort_t* __restrict__ A, const ushort_t* __restrict__ B,
            void* __restrict__ Cv, int mt, int K, int lda, int ldb, int ldc,
            long bsA, long bsB, long bsC)
{
    extern __shared__ ushort_t smem[];   // 3 bufs x (A 8192 + B 16384) ushorts

    const int nwg  = gridDim.x;
    const int orig = blockIdx.x;
    int wgid = orig;
    if (nwg >= 8) {
        const int q = nwg >> 3, r = nwg & 7;
        const int xcd = orig & 7, i = orig >> 3;
        wgid = (xcd < r ? xcd * (q + 1) : r * (q + 1) + (xcd - r) * q) + i;
    }
    const int m0 = (wgid % mt) * 128;
    const int n0 = (wgid / mt) * 256;

    A += (long)blockIdx.z * bsA;
    B += (long)blockIdx.z * bsB;

    const int tid  = threadIdx.x;
    const int lane = tid & 63;
    const int wid  = tid >> 6;
    const int wm   = wid >> 2, wn = wid & 3;
    const int cg   = lane >> 4, cl = lane & 15;
    const int lr   = lane >> 3;
    const int lcc  = (lane & 7) * 8;

    const int nt = K >> 6;

    auto stage = [&](int kt, int buf, int part) {
        ushort_t* base = smem + buf * 24576;
        const int k0 = kt * 64;
        if (part < 2) {
            const int rbase = part * 64 + wid * 8;
            const int row   = rbase + lr;
            const int col   = lcc ^ ((row & 7) << 3);
            GLD_LDS16(&A[(long)(m0 + row) * lda + k0 + col], base + rbase * 64);
        } else {
            const int rbase = (part - 2) * 64 + wid * 8;
            const int row   = rbase + lr;
            const int col   = lcc ^ ((row & 7) << 3);
            GLD_LDS16(&B[(long)(n0 + row) * ldb + k0 + col],
                      base + 8192 + rbase * 64);
        }
    };

    #pragma unroll
    for (int p = 0; p < 6; ++p) stage(0, 0, p);
    #pragma unroll
    for (int p = 0; p < 6; ++p) stage(1, 1, p);
    asm volatile("s_waitcnt vmcnt(6)" ::: "memory");
    __builtin_amdgcn_s_barrier();

    f32x4 acc[4][4] = {};

    for (int t = 0; t < nt; ++t) {
        const ushort_t* Aq = smem + (t % 3) * 24576;
        const ushort_t* Bq = Aq + 8192;
        const int sbuf = (t + 2) % 3;
        const bool do_stage = (t + 2 < nt);

        bf16x8 breg[4][2];
        #pragma unroll
        for (int p = 0; p < 4; ++p) {
            const int rowA = wm * 64 + p * 16 + cl;
            bf16x8 aA[2];
            #pragma unroll
            for (int kk = 0; kk < 2; ++kk)
                aA[kk] = __builtin_bit_cast(bf16x8, *(const us8*)&Aq[
                    rowA * 64 + ((kk * 32 + cg * 8) ^ ((rowA & 7) << 3))]);
            if (p == 0) {
                #pragma unroll
                for (int nj = 0; nj < 4; ++nj) {
                    const int rowB = wn * 64 + nj * 16 + cl;
                    #pragma unroll
                    for (int kk = 0; kk < 2; ++kk)
                        breg[nj][kk] = __builtin_bit_cast(bf16x8, *(const us8*)&Bq[
                            rowB * 64 + ((kk * 32 + cg * 8) ^ ((rowB & 7) << 3))]);
                }
            }
            if (do_stage) {
                if (p == 0)      { stage(t + 2, sbuf, 0); stage(t + 2, sbuf, 1); }
                else if (p == 1) { stage(t + 2, sbuf, 2); stage(t + 2, sbuf, 3); }
                else if (p == 2) { stage(t + 2, sbuf, 4); }
                else             { stage(t + 2, sbuf, 5); }
            }
            __builtin_amdgcn_s_setprio(1);
            #pragma unroll
            for (int nj = 0; nj < 4; ++nj)
                #pragma unroll
                for (int kk = 0; kk < 2; ++kk)
                    acc[p][nj] = __builtin_amdgcn_mfma_f32_16x16x32_bf16(
                        aA[kk], breg[nj][kk], acc[p][nj], 0, 0, 0);
            __builtin_amdgcn_s_setprio(0);
            __builtin_amdgcn_s_barrier();
        }
        if (do_stage) asm volatile("s_waitcnt vmcnt(6)" ::: "memory");
        else          asm volatile("s_waitcnt vmcnt(0)" ::: "memory");
        __builtin_amdgcn_s_barrier();
    }

    const int rb = m0 + wm * 64 + cg * 4;
    const int cb = n0 + wn * 64 + cl;

    #pragma unroll
    for (int mi = 0; mi < 4; ++mi) {
        #pragma unroll
        for (int nj = 0; nj < 4; ++nj) {
            const int colg = cb + nj * 16;
            if (EPI == EPI_QKV) {
                ushort_t* Q = (ushort_t*)Cv;
                if (n0 < 1024) {
                    #pragma unroll
                    for (int r = 0; r < 4; ++r)
                        Q[(long)(rb + mi * 16 + r) * 1024 + colg] = f2bf(acc[mi][nj][r]);
                } else if (n0 < 2048) {
                    #pragma unroll
                    for (int r = 0; r < 4; ++r)
                        Q[2097152 + (long)(rb + mi * 16 + r) * 1024 + (colg - 1024)] =
                            f2bf(acc[mi][nj][r]);
                } else {
                    ushort_t* Vt = Q + 4194304;
                    const int rowg = rb + mi * 16;
                    const long boff = (long)(rowg >> 10) * 1048576;
                    us4 o4;
                    #pragma unroll
                    for (int r = 0; r < 4; ++r) o4[r] = f2bf(acc[mi][nj][r]);
                    *(us4*)&Vt[boff + (long)(colg - 2048) * 1024 + (rowg & 1023)] = o4;
                }
            } else {
                #pragma unroll
                for (int r = 0; r < 4; ++r) {
                    const int  rowg = rb + mi * 16 + r;
                    const long off  = (long)rowg * ldc + colg;
                    const float val = acc[mi][nj][r];
                    if (EPI == EPI_F32) {
                        ((float*)Cv)[(long)blockIdx.z * bsC + off] = val;
                    } else if (EPI == EPI_GELU) {
                        float g = 0.5f * val * (1.0f + erff(val * 0.70710678118654752f));
                        ((ushort_t*)Cv)[off] = f2bf(g);
                    } else {
                        ((ushort_t*)Cv)[off] = f2bf(val);
                    }
                }
            }
        }
    }
}

// ---------------------------------------------------------------------------
// m97-style 64-row GEMM for Wo (full-fill 256-block grid, K=1024).
// Now writes pure f32 partial (no RMW on h).
// ---------------------------------------------------------------------------
template<int EPI, int MT>
__global__ __launch_bounds__(256)
void gemm128(const ushort_t* __restrict__ A, const ushort_t* __restrict__ B,
             void* __restrict__ Cv, int K, int lda, int ldb, int ldc)
{
    const int m0 = blockIdx.x * (MT * 32);
    const int n0 = blockIdx.y * 128;

    __shared__ __align__(16) ushort_t As[MT * 32][64];
    __shared__ __align__(16) ushort_t Bs[128][64];

    const int tid  = threadIdx.x;
    const int lane = tid & 63;
    const int wid  = tid >> 6;
    const int wr   = wid >> 1, wc = wid & 1;
    const int lr   = lane >> 3;
    const int lc   = (lane & 7) * 8;
    const int cg   = lane >> 4;
    const int cl   = lane & 15;

    f32x4 acc[MT][4] = {};

    for (int k0 = 0; k0 < K; k0 += 64) {
        #pragma unroll
        for (int j = 0; j < MT; ++j) {
            const int r = wid * (8 * MT) + j * 8;
            GLD_LDS16(&A[(long)(m0 + r + lr) * lda + k0 + lc], &As[r][0]);
        }
        #pragma unroll
        for (int j = 0; j < 4; ++j) {
            const int r = wid * 32 + j * 8;
            GLD_LDS16(&B[(long)(n0 + r + lr) * ldb + k0 + lc], &Bs[r][0]);
        }
        __syncthreads();
        #pragma unroll
        for (int kk = 0; kk < 2; ++kk) {
            const int krd = kk * 32 + cg * 8;
            bf16x8 af[MT], bfr[4];
            #pragma unroll
            for (int mi = 0; mi < MT; ++mi)
                af[mi] = __builtin_bit_cast(bf16x8,
                    *(const us8*)&As[wr * (MT * 16) + mi * 16 + cl][krd]);
            #pragma unroll
            for (int nj = 0; nj < 4; ++nj)
                bfr[nj] = __builtin_bit_cast(bf16x8,
                    *(const us8*)&Bs[wc * 64 + nj * 16 + cl][krd]);
            #pragma unroll
            for (int mi = 0; mi < MT; ++mi)
                #pragma unroll
                for (int nj = 0; nj < 4; ++nj)
                    acc[mi][nj] = __builtin_amdgcn_mfma_f32_16x16x32_bf16(
                        af[mi], bfr[nj], acc[mi][nj], 0, 0, 0);
        }
        __syncthreads();
    }

    const int rb = m0 + wr * (MT * 16) + cg * 4;
    const int cb = n0 + wc * 64 + cl;

    #pragma unroll
    for (int mi = 0; mi < MT; ++mi)
        #pragma unroll
        for (int nj = 0; nj < 4; ++nj)
            #pragma unroll
            for (int r = 0; r < 4; ++r) {
                const long off = (long)(rb + mi * 16 + r) * ldc + cb + nj * 16;
                const float val = acc[mi][nj][r];
                if (EPI == EPI_ADDF32)      ((float*)Cv)[off] += val;
                else if (EPI == EPI_F32)    ((float*)Cv)[off] = val;
                else                        ((ushort_t*)Cv)[off] = f2bf(val);
            }
}

// ---------------------------------------------------------------------------
// Fused causal flash attention v2 (log2 softmax, defer-max, hoisted V loads).
// ---------------------------------------------------------------------------
#define ATT_SCL 0.1803368805f   // 0.125 * log2(e)
#define ATT_THR 12.0f

__global__ __launch_bounds__(256)
void flash_attn(const ushort_t* __restrict__ qb, const ushort_t* __restrict__ kb,
                const ushort_t* __restrict__ vT, ushort_t* __restrict__ ob)
{
    const int qt = gridDim.x - 1 - blockIdx.x;
    const int hh = blockIdx.y;
    const int bb = blockIdx.z;
    const int lane = threadIdx.x & 63;
    const int w    = threadIdx.x >> 6;
    const int cg   = lane >> 4;
    const int cl   = lane & 15;

    __shared__ __align__(16) ushort_t P_lds[4][16][72];

    const int q0 = qt * 64;
    const long tokQ = (long)bb * 1024 + q0 + w * 16 + cl;

    bf16x8 qf[2];
    #pragma unroll
    for (int kk = 0; kk < 2; ++kk)
        qf[kk] = __builtin_bit_cast(bf16x8,
            *(const us8*)&qb[tokQ * 1024 + hh * 64 + kk * 32 + cg * 8]);

    const ushort_t* kbase = kb + (long)bb * 1048576 + hh * 64;
    const ushort_t* vbase = vT + (long)bb * 1048576 + (long)hh * 65536;

    f32x4 o[4] = {};
    float m4[4], l4[4];
    #pragma unroll
    for (int r = 0; r < 4; ++r) { m4[r] = -1e30f; l4[r] = 0.0f; }

    for (int tt = 0; tt <= qt; ++tt) {
        const int t0 = tt * 64;
        f32x4 s[4] = {};
        __builtin_amdgcn_s_setprio(1);
        #pragma unroll
        for (int nj = 0; nj < 4; ++nj) {
            const ushort_t* kp = kbase + (long)(t0 + nj * 16 + cl) * 1024 + cg * 8;
            bf16x8 kf0 = __builtin_bit_cast(bf16x8, *(const us8*)kp);
            bf16x8 kf1 = __builtin_bit_cast(bf16x8, *(const us8*)(kp + 32));
            s[nj] = __builtin_amdgcn_mfma_f32_16x16x32_bf16(qf[0], kf0, s[nj], 0, 0, 0);
            s[nj] = __builtin_amdgcn_mfma_f32_16x16x32_bf16(qf[1], kf1, s[nj], 0, 0, 0);
        }
        __builtin_amdgcn_s_setprio(0);

        bf16x8 vreg[4][2];
        #pragma unroll
        for (int nj = 0; nj < 4; ++nj) {
            const ushort_t* vp = vbase + (long)(nj * 16 + cl) * 1024 + t0 + cg * 8;
            vreg[nj][0] = __builtin_bit_cast(bf16x8, *(const us8*)vp);
            vreg[nj][1] = __builtin_bit_cast(bf16x8, *(const us8*)(vp + 32));
        }

        const bool diag = (tt == qt);
        float pm[4] = {-3e30f, -3e30f, -3e30f, -3e30f};
        #pragma unroll
        for (int nj = 0; nj < 4; ++nj)
            #pragma unroll
            for (int r = 0; r < 4; ++r) {
                float v = s[nj][r] * ATT_SCL;
                if (diag && (t0 + nj * 16 + cl) > (q0 + w * 16 + cg * 4 + r))
                    v = -3e30f;
                s[nj][r] = v;
                pm[r] = fmaxf(pm[r], v);
            }
        #pragma unroll
        for (int r = 0; r < 4; ++r)
            #pragma unroll
            for (int msk = 1; msk < 16; msk <<= 1)
                pm[r] = fmaxf(pm[r], __shfl_xor(pm[r], msk));

        const bool grow = (pm[0] > m4[0] + ATT_THR) || (pm[1] > m4[1] + ATT_THR)
                       || (pm[2] > m4[2] + ATT_THR) || (pm[3] > m4[3] + ATT_THR);
        if (__any(grow)) {
            #pragma unroll
            for (int r = 0; r < 4; ++r) {
                const float mn = fmaxf(m4[r], pm[r]);
                const float al = __builtin_amdgcn_exp2f(m4[r] - mn);
                m4[r] = mn;
                l4[r] *= al;
                #pragma unroll
                for (int nj = 0; nj < 4; ++nj) o[nj][r] *= al;
            }
        }
        float ps[4] = {0.0f, 0.0f, 0.0f, 0.0f};
        #pragma unroll
        for (int nj = 0; nj < 4; ++nj)
            #pragma unroll
            for (int r = 0; r < 4; ++r) {
                const float p = __builtin_amdgcn_exp2f(s[nj][r] - m4[r]);
                s[nj][r] = p;
                ps[r] += p;
            }
        #pragma unroll
        for (int r = 0; r < 4; ++r) {
            #pragma unroll
            for (int msk = 1; msk < 16; msk <<= 1)
                ps[r] += __shfl_xor(ps[r], msk);
            l4[r] += ps[r];
        }
        #pragma unroll
        for (int nj = 0; nj < 4; ++nj)
            #pragma unroll
            for (int r = 0; r < 4; ++r)
                P_lds[w][cg * 4 + r][nj * 16 + cl] = bf16u(s[nj][r]);
        asm volatile("s_waitcnt lgkmcnt(0)" ::: "memory");
        __builtin_amdgcn_sched_barrier(0);
        bf16x8 pa[2];
        #pragma unroll
        for (int kk = 0; kk < 2; ++kk)
            pa[kk] = __builtin_bit_cast(bf16x8,
                *(const us8*)&P_lds[w][cl][kk * 32 + cg * 8]);
        __builtin_amdgcn_s_setprio(1);
        #pragma unroll
        for (int nj = 0; nj < 4; ++nj) {
            o[nj] = __builtin_amdgcn_mfma_f32_16x16x32_bf16(pa[0], vreg[nj][0], o[nj], 0, 0, 0);
            o[nj] = __builtin_amdgcn_mfma_f32_16x16x32_bf16(pa[1], vreg[nj][1], o[nj], 0, 0, 0);
        }
        __builtin_amdgcn_s_setprio(0);
    }

    #pragma unroll
    for (int r = 0; r < 4; ++r) {
        const float inv = 1.0f / l4[r];
        const long tok = (long)bb * 1024 + q0 + w * 16 + cg * 4 + r;
        #pragma unroll
        for (int nj = 0; nj < 4; ++nj)
            ob[tok * 1024 + hh * 64 + nj * 16 + cl] = bf16u(o[nj][r] * inv);
    }
}

// ---------------------------------------------------------------------------
// Transpose + f32->bf16, vectorized us4 writes (r14).
// ---------------------------------------------------------------------------
__global__ __launch_bounds__(256)
void transpose_conv(const float* __restrict__ in, ushort_t* __restrict__ out,
                    long ldin, long ldout, long bsin, long bsout,
                    long bsout_hi, int zmod)
{
    __shared__ float tile[32][132];
    const int tx = threadIdx.x, ty = threadIdx.y;
    const long bin  = (long)blockIdx.z * bsin;
    const long bout = (long)(blockIdx.z % zmod) * bsout
                    + (long)(blockIdx.z / zmod) * bsout_hi;
    const int n0 = blockIdx.x * 32, k0 = blockIdx.y * 128;
    #pragma unroll
    for (int i = 0; i < 16; ++i)
        tile[tx][ty + i * 8] = in[bin + (long)(k0 + ty + i * 8) * ldin + n0 + tx];
    __syncthreads();
    #pragma unroll
    for (int i = 0; i < 4; ++i) {
        const int n = ty + i * 8;
        const f32x4 v = *(const f32x4*)&tile[n][tx * 4];
        us4 o4;
        o4[0] = bf16u(v[0]); o4[1] = bf16u(v[1]);
        o4[2] = bf16u(v[2]); o4[3] = bf16u(v[3]);
        *(us4*)&out[bout + (long)(n0 + n) * ldout + k0 + tx * 4] = o4;
    }
}

// ---------------------------------------------------------------------------
__global__ __launch_bounds__(256)
void embed_kernel(const int* __restrict__ x, const float* __restrict__ emb,
                  const float* __restrict__ pos, float* __restrict__ h)
{
    const int row = blockIdx.x, tid = threadIdx.x;
    const int s = row & 1023;
    const int idx = x[row];
    const float4 e = ((const float4*)(emb + (long)idx * 1024))[tid];
    const float4 p = ((const float4*)(pos + (long)s * 1024))[tid];
    float4 o; o.x = e.x + p.x; o.y = e.y + p.y; o.z = e.z + p.z; o.w = e.w + p.w;
    ((float4*)(h + (long)row * 1024))[tid] = o;
}

// ---------------------------------------------------------------------------
// ln_red<NP>: h <- h + sum_{p<NP} part[p];  z = bf16(LN(h));  h written back.
// NP=0 is the plain LN (no partials, h unchanged).
// ---------------------------------------------------------------------------
template<int NP>
__global__ __launch_bounds__(256)
void ln_red_kernel(float* __restrict__ h, const float* __restrict__ part,
                   long pstride, const float* __restrict__ g,
                   const float* __restrict__ b, ushort_t* __restrict__ z)
{
    const int row = blockIdx.x, tid = threadIdx.x;
    const long roff = (long)row * 1024 + tid * 4;
    float4 v = *(const float4*)&h[roff];
    #pragma unroll
    for (int p = 0; p < NP; ++p) {
        const float4 a = *(const float4*)&part[p * pstride + roff];
        v.x += a.x; v.y += a.y; v.z += a.z; v.w += a.w;
    }
    if (NP > 0) *(float4*)&h[roff] = v;

    float s  = v.x + v.y + v.z + v.w;
    float sq = v.x * v.x + v.y * v.y + v.z * v.z + v.w * v.w;
    #pragma unroll
    for (int o = 32; o > 0; o >>= 1) { s += __shfl_down(s, o); sq += __shfl_down(sq, o); }
    __shared__ float ls[4], lq[4];
    if ((tid & 63) == 0) { ls[tid >> 6] = s; lq[tid >> 6] = sq; }
    __syncthreads();
    s  = ls[0] + ls[1] + ls[2] + ls[3];
    sq = lq[0] + lq[1] + lq[2] + lq[3];
    const float mu   = s * (1.0f / 1024.0f);
    const float var  = sq * (1.0f / 1024.0f) - mu * mu;
    const float rstd = rsqrtf(var + LN_EPS);
    const float4 gg = ((const float4*)g)[tid];
    const float4 bb = ((const float4*)b)[tid];
    us4 o4;
    o4[0] = f2bf((v.x - mu) * rstd * gg.x + bb.x);
    o4[1] = f2bf((v.y - mu) * rstd * gg.y + bb.y);
    o4[2] = f2bf((v.z - mu) * rstd * gg.z + bb.z);
    o4[3] = f2bf((v.w - mu) * rstd * gg.w + bb.w);
    *(us4*)&z[roff] = o4;
}

// ---------------------------------------------------------------------------
extern "C" void kernel_launch(void* const* d_in, const int* in_sizes, int n_in,
                              void* d_out, int out_size, void* d_ws, size_t ws_size,
                              hipStream_t stream)
{
    const int*   x   = (const int*)  d_in[0];
    const float* emb = (const float*)d_in[1];
    const float* pos = (const float*)d_in[2];
    const float* Wq  = (const float*)d_in[3];
    const float* Wk  = (const float*)d_in[4];
    const float* Wv  = (const float*)d_in[5];
    const float* Wo  = (const float*)d_in[6];
    const float* g1  = (const float*)d_in[7];
    const float* b1  = (const float*)d_in[8];
    const float* g2  = (const float*)d_in[9];
    const float* b2  = (const float*)d_in[10];
    const float* W1  = (const float*)d_in[11];
    const float* W2  = (const float*)d_in[12];
    const float* gf  = (const float*)d_in[13];
    const float* bfp = (const float*)d_in[14];
    const float* Wf  = (const float*)d_in[15];
    float* out = (float*)d_out;

    char* ws = (char*)d_ws;
    size_t off = 0;
    auto alloc = [&](size_t bytes) {
        char* p = ws + off;
        off = (off + bytes + 255) & ~(size_t)255;
        return p;
    };
    ushort_t* WqkvT = (ushort_t*)alloc(4UL * 3145728 * 2);   // [L][3][1024][1024]
    ushort_t* WoT   = (ushort_t*)alloc(4UL * 1048576 * 2);
    ushort_t* W1T   = (ushort_t*)alloc(4UL * 6291456 * 2);
    ushort_t* W2T   = (ushort_t*)alloc(4UL * 6291456 * 2);
    ushort_t* WfT   = (ushort_t*)alloc(32768000UL * 2);
    float*    h     = (float*)   alloc(2048UL * 1024 * 4);
    ushort_t* z     = (ushort_t*)alloc(2048UL * 1024 * 2);
    ushort_t* qb    = (ushort_t*)alloc(3UL * 2048 * 1024 * 2); // q | k | vT
    ushort_t* kb    = qb + 2097152;
    ushort_t* vT    = qb + 4194304;
    ushort_t* ob    = (ushort_t*)alloc(2048UL * 1024 * 2);
    ushort_t* ub    = (ushort_t*)alloc(2048UL * 6144 * 2);
    float*    wob   = (float*)   alloc(2048UL * 1024 * 4);        // Wo partial
    float*    fp    = (float*)   alloc(4UL * 2048 * 1024 * 4);    // FFN-down partials
    (void)ws_size; (void)in_sizes; (void)n_in; (void)out_size;

    const int LDS8P = 2 * 32768 * 2;   // 128 KiB for gemm8ph
    const int LDS3B = 3 * 49152;       // 144 KiB for gemm8p
    hipFuncSetAttribute((const void*)&gemm8ph<EPI_F32>,
                        hipFuncAttributeMaxDynamicSharedMemorySize, LDS8P);
    hipFuncSetAttribute((const void*)&gemm8ph<EPI_GELU>,
                        hipFuncAttributeMaxDynamicSharedMemorySize, LDS8P);
    hipFuncSetAttribute((const void*)&gemm8p<EPI_QKV>,
                        hipFuncAttributeMaxDynamicSharedMemorySize, LDS3B);
    hipFuncSetAttribute((const void*)&gemm8p<EPI_F32>,
                        hipFuncAttributeMaxDynamicSharedMemorySize, LDS3B);

    const dim3 tb(32, 8);
    // q/k/v -> fused [L][3][1024 out][1024 K] (B^T layout)
    transpose_conv<<<dim3(2,   8, 64), tb, 0, stream>>>(Wq, WqkvT,           64, 1024, 65536, 65536, 3145728, 16);
    transpose_conv<<<dim3(2,   8, 64), tb, 0, stream>>>(Wk, WqkvT + 1048576, 64, 1024, 65536, 65536, 3145728, 16);
    transpose_conv<<<dim3(2,   8, 64), tb, 0, stream>>>(Wv, WqkvT + 2097152, 64, 1024, 65536, 65536, 3145728, 16);
    transpose_conv<<<dim3(32,  8,  4), tb, 0, stream>>>(Wo, WoT, 1024,  1024, 1048576, 1048576, 0, 4);
    transpose_conv<<<dim3(192, 8,  4), tb, 0, stream>>>(W1, W1T, 6144,  1024, 6291456, 6291456, 0, 4);
    transpose_conv<<<dim3(32, 48,  4), tb, 0, stream>>>(W2, W2T, 1024,  6144, 6291456, 6291456, 0, 4);
    transpose_conv<<<dim3(1000,8,  1), tb, 0, stream>>>(Wf, WfT, 32000, 1024, 0,       0,       0, 1);

    embed_kernel<<<2048, 256, 0, stream>>>(x, emb, pos, h);

    for (int l = 0; l < 4; ++l) {
        const size_t wff = (size_t)l * 6291456;

        // LN1: plain for layer 0; for l>0 it also folds in the previous
        // layer's FFN-down partials (h += sum fp).
        if (l == 0)
            ln_red_kernel<0><<<2048, 256, 0, stream>>>(
                h, fp, 2097152, g1, b1, z);
        else
            ln_red_kernel<4><<<2048, 256, 0, stream>>>(
                h, fp, 2097152, g1 + l * 1024, b1 + l * 1024, z);

        // fused QKV: [2048,3072] = z @ WqkvT^T   (192 blocks)
        gemm8p<EPI_QKV><<<dim3(16 * 12), 512, LDS3B, stream>>>(
            z, WqkvT + (size_t)l * 3145728, qb, 16, 1024, 1024, 1024, 1024, 0, 0, 0);

        flash_attn<<<dim3(16, 16, 2), 256, 0, stream>>>(qb, kb, vT, ob);

        // wob = o @ Wo  (pure f32 partial, no RMW)
        gemm128<EPI_F32, 2><<<dim3(32, 8), 256, 0, stream>>>(
            ob, WoT + (size_t)l * 1048576, wob, 1024, 1024, 1024, 1024);

        // LN2 + residual fold: h += wob; z = LN(h)
        ln_red_kernel<1><<<2048, 256, 0, stream>>>(
            h, wob, 0, g2 + l * 1024, b2 + l * 1024, z);

        // u = gelu(z @ W1)   (192 blocks, 8-phase)
        gemm8ph<EPI_GELU><<<dim3(8 * 24), 512, LDS8P, stream>>>(
            z, W1T + wff, ub, 8, 1024, 1024, 1024, 6144);
        // fp[z] = u @ W2 partials, K split 4 ways (256 blocks, pure writes)
        gemm8p<EPI_F32><<<dim3(16 * 4, 1, 4), 512, LDS3B, stream>>>(
            ub, W2T + wff, fp, 16, 1536, 6144, 6144, 1024, 1536, 1536, 2097152);
    }

    // final LN folds layer-3 FFN-down partials
    ln_red_kernel<4><<<2048, 256, 0, stream>>>(h, fp, 2097152, gf, bfp, z);
    // logits = z @ Wf -> f32 [2048, 32000]   (1000 blocks, 8-phase, bounce epi)
    gemm8ph<EPI_F32><<<dim3(8 * 125), 512, LDS8P, stream>>>(
        z, WfT, out, 8, 1024, 1024, 1024, 32000);
}